// Round 11
// baseline (180.228 us; speedup 1.0000x reference)
//
#include <hip/hip_runtime.h>
#include <math.h>

#define SEQ  1024
#define IND  256
#define CC   1024
#define NH   8
#define HD   128
#define BH   64      // BATCH*NH

typedef __bf16 bf16x8 __attribute__((ext_vector_type(8)));
typedef __bf16 bf16x4 __attribute__((ext_vector_type(4)));
typedef float  f32x4  __attribute__((ext_vector_type(4)));
typedef unsigned short u16;

static constexpr float RSDK = 0.08838834764831845f;  // 1/sqrt(128)

__device__ __forceinline__ u16 f2bf(float f) {
    unsigned int u = __float_as_uint(f);
    u += 0x7fffu + ((u >> 16) & 1u);   // round-to-nearest-even
    return (u16)(u >> 16);
}

__device__ __forceinline__ unsigned cvt_pk_bf16(float lo, float hi) {
    unsigned r;
    asm("v_cvt_pk_bf16_f32 %0, %1, %2" : "=v"(r) : "v"(lo), "v"(hi));
    return r;
}

// ---------------------------------------------------------------------------
// P0: fused prep. 1D grid 2944, block 256.
//   id <  2048          : x fp32 -> bf16 (4 elems/thread)
//   2048 <= id < 2816   : wq/wk/wv [256][1024] -> bf16 [1024][256] transpose
//   2816 <= id < 2944   : proj_w [1024][128]  -> bf16 [128][1024] transpose
// ---------------------------------------------------------------------------
__global__ __launch_bounds__(256) void prep_kernel(
    const float* __restrict__ x, u16* __restrict__ xb,
    const float* __restrict__ w0, const float* __restrict__ w1, const float* __restrict__ w2,
    u16* __restrict__ o0, u16* __restrict__ o1, u16* __restrict__ o2,
    const float* __restrict__ pw, u16* __restrict__ pT)
{
    __shared__ float tile[32][33];
    const int id = blockIdx.x;

    if (id < 2048) {
        const int i = id * 256 + threadIdx.x;
        float4 v = ((const float4*)x)[i];
        ushort4 o;
        o.x = f2bf(v.x); o.y = f2bf(v.y); o.z = f2bf(v.z); o.w = f2bf(v.w);
        ((ushort4*)xb)[i] = o;
        return;
    }

    const float* in; u16* out; int R, C, c0, r0;
    if (id < 2816) {
        const int rem = id - 2048;
        const int z = rem >> 8;              // 0..2
        const int rem2 = rem & 255;
        in  = (z == 0) ? w0 : (z == 1) ? w1 : w2;
        out = (z == 0) ? o0 : (z == 1) ? o1 : o2;
        R = IND; C = CC;
        c0 = (rem2 & 31) * 32;               // 0..992
        r0 = (rem2 >> 5) * 32;               // 0..224
    } else {
        const int rem = id - 2816;
        in = pw; out = pT;
        R = CC; C = HD;
        c0 = (rem & 3) * 32;                 // 0..96
        r0 = (rem >> 2) * 32;                // 0..992
    }

    const int row = threadIdx.x >> 3, col4 = (threadIdx.x & 7) * 4;
    float4 v = *(const float4*)&in[(size_t)(r0 + row) * C + c0 + col4];
    tile[row][col4 + 0] = v.x; tile[row][col4 + 1] = v.y;
    tile[row][col4 + 2] = v.z; tile[row][col4 + 3] = v.w;
    __syncthreads();
    ushort4 o;
    o.x = f2bf(tile[col4 + 0][row]);
    o.y = f2bf(tile[col4 + 1][row]);
    o.z = f2bf(tile[col4 + 2][row]);
    o.w = f2bf(tile[col4 + 3][row]);
    *(ushort4*)&out[(size_t)(c0 + row) * R + r0 + col4] = o;
}

// ---------------------------------------------------------------------------
// K1: QKV MFMA GEMM — R23 hybrid (kept; neutral-vs-R12 within noise, but
// theoretically sounder stores). M=8192,N=1024,K=256. grid (64,8,3),
// block 256. 128x128 tile, BK=64, PADDED rows (stride 72 u16) reg-staged.
// Q/K use SWAPPED operands mfma(bf, af) -> lane holds 4 consecutive d ->
// epilogue is 16 ushort4 stores/lane. V unswapped + transposed ushort4 path.
// ---------------------------------------------------------------------------
#define QKV_LDW 72
__global__ __launch_bounds__(256) void qkv_kernel(
    const u16* __restrict__ xb,
    const u16* __restrict__ wT0, const u16* __restrict__ wT1, const u16* __restrict__ wT2,
    const float* __restrict__ b0, const float* __restrict__ b1, const float* __restrict__ b2,
    u16* __restrict__ q_out, u16* __restrict__ k_out, u16* __restrict__ vt_out)
{
    const int mat = blockIdx.z;
    const u16* wT  = (mat == 0) ? wT0 : (mat == 1) ? wT1 : wT2;
    const float* wb = (mat == 0) ? b0 : (mat == 1) ? b1 : b2;
    const float scale = (mat == 0) ? RSDK : 1.0f;

    __shared__ __align__(16) u16 As[128 * QKV_LDW];
    __shared__ __align__(16) u16 Bs[128 * QKV_LDW];

    const int tid = threadIdx.x;
    const int lane = tid & 63, wave = tid >> 6;
    const int ln = lane & 15, quad = lane >> 4;
    const int m0 = blockIdx.x * 128;
    const int n0 = blockIdx.y * 128;
    const int wm = (wave & 1) * 64;
    const int wn = (wave >> 1) * 64;

    f32x4 acc[4][4];
    #pragma unroll
    for (int mb = 0; mb < 4; ++mb)
        #pragma unroll
        for (int nb = 0; nb < 4; ++nb)
            #pragma unroll
            for (int r = 0; r < 4; ++r) acc[mb][nb][r] = 0.0f;

    const int r8 = tid >> 3, pb8 = tid & 7;   // row-within-32, 16B block

    const u16* ag = xb + (size_t)(m0 + r8) * IND + pb8 * 8;
    const u16* bg = wT + (size_t)(n0 + r8) * IND + pb8 * 8;

    bf16x8 pa[4], pbv[4];
    #pragma unroll
    for (int c = 0; c < 4; ++c) {
        pa[c]  = *(const bf16x8*)(ag + (size_t)c * 32 * IND);
        pbv[c] = *(const bf16x8*)(bg + (size_t)c * 32 * IND);
    }

    for (int kt = 0; kt < 4; ++kt) {
        __syncthreads();
        #pragma unroll
        for (int c = 0; c < 4; ++c) {
            *(bf16x8*)(As + (size_t)(c * 32 + r8) * QKV_LDW + pb8 * 8) = pa[c];
            *(bf16x8*)(Bs + (size_t)(c * 32 + r8) * QKV_LDW + pb8 * 8) = pbv[c];
        }
        __syncthreads();
        if (kt < 3) {
            #pragma unroll
            for (int c = 0; c < 4; ++c) {
                pa[c]  = *(const bf16x8*)(ag + (size_t)c * 32 * IND + (kt + 1) * 64);
                pbv[c] = *(const bf16x8*)(bg + (size_t)c * 32 * IND + (kt + 1) * 64);
            }
        }
        #pragma unroll
        for (int ks = 0; ks < 2; ++ks) {
            bf16x8 af[4], bf[4];
            #pragma unroll
            for (int mb = 0; mb < 4; ++mb)
                af[mb] = *(const bf16x8*)(As + (size_t)(wm + mb * 16 + ln) * QKV_LDW
                                             + (ks * 4 + quad) * 8);
            #pragma unroll
            for (int nb = 0; nb < 4; ++nb)
                bf[nb] = *(const bf16x8*)(Bs + (size_t)(wn + nb * 16 + ln) * QKV_LDW
                                             + (ks * 4 + quad) * 8);
            if (mat != 2) {
                // swapped: acc[mb][nb][r] = C[m=mb*16+ln][n=nb*16+quad*4+r]
                #pragma unroll
                for (int mb = 0; mb < 4; ++mb)
                    #pragma unroll
                    for (int nb = 0; nb < 4; ++nb)
                        acc[mb][nb] = __builtin_amdgcn_mfma_f32_16x16x32_bf16(
                            bf[nb], af[mb], acc[mb][nb], 0, 0, 0);
            } else {
                // unswapped: acc[mb][nb][r] = C[m=mb*16+quad*4+r][n=nb*16+ln]
                #pragma unroll
                for (int mb = 0; mb < 4; ++mb)
                    #pragma unroll
                    for (int nb = 0; nb < 4; ++nb)
                        acc[mb][nb] = __builtin_amdgcn_mfma_f32_16x16x32_bf16(
                            af[mb], bf[nb], acc[mb][nb], 0, 0, 0);
            }
        }
    }

    if (mat != 2) {
        u16* outp = (mat == 0) ? q_out : k_out;
        const int h = n0 >> 7;   // one head per n-tile
        float4 bv[4];
        #pragma unroll
        for (int nb = 0; nb < 4; ++nb)
            bv[nb] = *(const float4*)&wb[n0 + wn + nb * 16 + quad * 4];
        #pragma unroll
        for (int mb = 0; mb < 4; ++mb) {
            const int m = m0 + wm + mb * 16 + ln;
            const int b = m >> 10, tok = m & 1023;
            u16* orow = outp + ((size_t)(b * NH + h) * SEQ + tok) * HD;
            #pragma unroll
            for (int nb = 0; nb < 4; ++nb) {
                const int d0 = wn + nb * 16 + quad * 4;
                ushort4 o;
                o.x = f2bf((acc[mb][nb][0] + bv[nb].x) * scale);
                o.y = f2bf((acc[mb][nb][1] + bv[nb].y) * scale);
                o.z = f2bf((acc[mb][nb][2] + bv[nb].z) * scale);
                o.w = f2bf((acc[mb][nb][3] + bv[nb].w) * scale);
                *(ushort4*)&orow[d0] = o;
            }
        }
    } else {
        // V: fused transpose -> Vt [bh][d][n]; 4 consecutive tokens per store
        #pragma unroll
        for (int nb = 0; nb < 4; ++nb) {
            const int c = n0 + wn + nb * 16 + ln;
            const float bv = wb[c];
            const int h = c >> 7, d = c & 127;
            #pragma unroll
            for (int mb = 0; mb < 4; ++mb) {
                const int m = m0 + wm + mb * 16 + quad * 4;
                const int b = m >> 10, tok0 = m & 1023;
                ushort4 o;
                o.x = f2bf(acc[mb][nb][0] + bv);
                o.y = f2bf(acc[mb][nb][1] + bv);
                o.z = f2bf(acc[mb][nb][2] + bv);
                o.w = f2bf(acc[mb][nb][3] + bv);
                *(ushort4*)&vt_out[((size_t)(b * NH + h) * HD + d) * SEQ + tok0] = o;
            }
        }
    }
}

// ---------------------------------------------------------------------------
// K2: flash attention, MFMA. R25: DOUBLE STAGING GRANULE, compute granule
// unchanged. Stage TWO 32-key tiles per barrier pair (Ks[2]/Vs[2], both
// written strictly between barrier1 and barrier2), then two back-to-back
// R20-exact 32-key compute granules with NO barrier between. Barrier pairs
// 32 -> 16. Rationale: attn pinned at ~58 us with LDS ~45% / MFMA ~23% /
// VALU ~28% (nothing saturated) -> barrier-convoy latency; R23 showed the
// COMPUTE granule must stay at 32 keys (doubling it lengthened the serial
// VALU/transpose chain: 57.5 -> 62.5); R18 showed single-barrier rotation
// races. This point keeps the R20 race invariant (writes between barriers,
// reads after, next overwrite after next barrier1) and the R20 per-granule
// working set. Key order & arithmetic bit-exact vs R20. LDS 37.9 KB,
// 512 blocks = 2 blocks/CU unchanged; +16 staging VGPRs.
// grid (64 bh, 8 q-blocks), block 256, launch_bounds(256,2); wave owns 32
// q-rows (2 q-tiles) sharing one set of K/V fragment reads.
// Unnormalized softmax (|s| <~ 10 << 88), p = exp(s), l in regs,
// in-register P via swapped QK^T + cvt_pk/permlane 4-quad transpose.
// Ks: [32 k][128 d] stride 136 u16; Vs: [128 d][32 k] stride 40 u16; x2.
// Closed frontiers: R18 single-barrier dbuf (RACE); R19 K-direct-global
// (2.4x); R21 key-split 512-thr (spill, 2.2x); R23 KVB=64 compute granule
// (+9%). SQ_LDS_BANK_CONFLICT is structural 2-way accounting — not a lever.
// Other negatives: XOR swizzle (R3/4), P pair-pack LDS (R7), V-direct (R9),
// bias-as-C (R13), exp2 fold (R14).
// ---------------------------------------------------------------------------
#define KVB    32
#define KS_LDW 136
#define VS_LDW 40
__global__ __launch_bounds__(256, 2) void attn_kernel(
    const u16* __restrict__ Q, const u16* __restrict__ K,
    const u16* __restrict__ Vt, const float* __restrict__ bias,
    u16* __restrict__ aout)
{
    __shared__ __align__(16) u16 Ks[2][KVB * KS_LDW];     // 2 x 8704 B
    __shared__ __align__(16) u16 Vs[2][128 * VS_LDW];     // 2 x 10240 B

    const int tid = threadIdx.x;
    const int lane = tid & 63, wave = tid >> 6;
    const int ln = lane & 15, quad = lane >> 4;
    const int bh = blockIdx.x;
    const int q0 = blockIdx.y * 128 + wave * 32;

    bf16x8 qf[2][4];
    #pragma unroll
    for (int mb = 0; mb < 2; ++mb) {
        const u16* qp = Q + ((size_t)bh * SEQ + q0 + mb * 16 + ln) * HD + quad * 8;
        #pragma unroll
        for (int ks = 0; ks < 4; ++ks) qf[mb][ks] = *(const bf16x8*)(qp + ks * 32);
    }

    f32x4 Oa[2][8];
    #pragma unroll
    for (int mb = 0; mb < 2; ++mb)
        #pragma unroll
        for (int db = 0; db < 8; ++db)
            #pragma unroll
            for (int r = 0; r < 4; ++r) Oa[mb][db][r] = 0.0f;
    float l_loc[2] = {0.0f, 0.0f};   // partial l for query ln, per q-tile

    const u16* Kg0 = K  + (size_t)bh * SEQ * HD;
    const u16* Vg0 = Vt + (size_t)bh * HD * SEQ;
    // bias rows for THIS lane's queries (ln per tile); float4 in key dim
    const float* brow0 = bias + (size_t)(q0 + ln) * SEQ + quad * 4;
    const float* brow1 = brow0 + (size_t)16 * SEQ;

    // staging indices (R17/R20-exact maps)
    const int r16 = tid >> 4, pb16 = tid & 15;   // K: 16 rows/pass
    const int r4  = tid >> 2, pb4  = tid & 3;    // V: 64 rows/pass

    const u16* kg = Kg0 + (size_t)r16 * HD + pb16 * 8;   // + kt*KVB*HD + c*16*HD
    const u16* vg = Vg0 + (size_t)r4 * SEQ + pb4 * 8;    // + c*64*SEQ + kt*KVB

    // prologue: tiles 0 and 1 into regs
    bf16x8 kp[2][2], vp[2][2];
    #pragma unroll
    for (int g2 = 0; g2 < 2; ++g2)
        #pragma unroll
        for (int c = 0; c < 2; ++c) {
            kp[g2][c] = *(const bf16x8*)(kg + (size_t)g2 * KVB * HD + (size_t)c * 16 * HD);
            vp[g2][c] = *(const bf16x8*)(vg + (size_t)c * 64 * SEQ + g2 * KVB);
        }

    // bias prefetch for kt=0: [mb][nb] = keys nb*16 + quad*4 + {0..3}
    float4 bpre[2][2];
    #pragma unroll
    for (int mb = 0; mb < 2; ++mb)
        #pragma unroll
        for (int nb = 0; nb < 2; ++nb)
            bpre[mb][nb] = *(const float4*)((mb ? brow1 : brow0) + nb * 16);

    for (int it = 0; it < 16; ++it) {
        __syncthreads();                      // barrier1: prev compute done
        #pragma unroll
        for (int g2 = 0; g2 < 2; ++g2)
            #pragma unroll
            for (int c = 0; c < 2; ++c) {
                *(bf16x8*)(Ks[g2] + (size_t)(c * 16 + r16) * KS_LDW + pb16 * 8) = kp[g2][c];
                *(bf16x8*)(Vs[g2] + (size_t)(c * 64 + r4) * VS_LDW + pb4 * 8)   = vp[g2][c];
            }
        __syncthreads();                      // barrier2: staging visible

        // prefetch tiles 2it+2, 2it+3 (two compute granules of cover)
        if (it < 15) {
            #pragma unroll
            for (int g2 = 0; g2 < 2; ++g2)
                #pragma unroll
                for (int c = 0; c < 2; ++c) {
                    const size_t t = (size_t)(2 * it + 2 + g2);
                    kp[g2][c] = *(const bf16x8*)(kg + t * KVB * HD + (size_t)c * 16 * HD);
                    vp[g2][c] = *(const bf16x8*)(vg + (size_t)c * 64 * SEQ + t * KVB);
                }
        }

        // ---- two back-to-back R20-exact 32-key compute granules ----
        #pragma unroll
        for (int g2 = 0; g2 < 2; ++g2) {
            const int kt = 2 * it + g2;
            const u16* ksb = Ks[g2];
            const u16* vsb = Vs[g2];

            // S^T = K Q^T (swapped); kf shared by both q-tiles
            float p8[2][2][4];
            #pragma unroll
            for (int nb = 0; nb < 2; ++nb) {
                const u16* kr = ksb + (size_t)(nb * 16 + ln) * KS_LDW;
                bf16x8 kf[4];
                #pragma unroll
                for (int ks = 0; ks < 4; ++ks)
                    kf[ks] = *(const bf16x8*)(kr + (ks * 4 + quad) * 8);
                #pragma unroll
                for (int mb = 0; mb < 2; ++mb) {
                    f32x4 s;
                    #pragma unroll
                    for (int r = 0; r < 4; ++r) s[r] = 0.0f;
                    #pragma unroll
                    for (int ks = 0; ks < 4; ++ks)
                        s = __builtin_amdgcn_mfma_f32_16x16x32_bf16(kf[ks], qf[mb][ks], s, 0, 0, 0);
                    #pragma unroll
                    for (int r = 0; r < 4; ++r) {
                        const float p = __expf(s[r] + bpre[mb][nb][r]);
                        l_loc[mb] += p;
                        p8[mb][nb][r] = p;
                    }
                }
            }

            // bias for kt+1 (after last use of bpre; hidden under PV)
            if (kt < 31) {
                #pragma unroll
                for (int mb = 0; mb < 2; ++mb)
                    #pragma unroll
                    for (int nb = 0; nb < 2; ++nb)
                        bpre[mb][nb] = *(const float4*)((mb ? brow1 : brow0)
                                                        + (kt + 1) * KVB + nb * 16);
            }

            // P -> A fragments: pure-register 4-quad transpose, per q-tile
            bf16x8 af[2];
            #pragma unroll
            for (int mb = 0; mb < 2; ++mb) {
                unsigned x0 = cvt_pk_bf16(p8[mb][0][0], p8[mb][0][1]);
                unsigned x1 = cvt_pk_bf16(p8[mb][0][2], p8[mb][0][3]);
                unsigned y0 = cvt_pk_bf16(p8[mb][1][0], p8[mb][1][1]);
                unsigned y1 = cvt_pk_bf16(p8[mb][1][2], p8[mb][1][3]);
                asm("v_permlane32_swap_b32 %0, %1" : "+v"(x0), "+v"(y0));
                asm("v_permlane32_swap_b32 %0, %1" : "+v"(x1), "+v"(y1));
                asm("v_permlane16_swap_b32 %0, %1" : "+v"(x0), "+v"(y0));
                asm("v_permlane16_swap_b32 %0, %1" : "+v"(x1), "+v"(y1));
                union { unsigned u[4]; bf16x8 v; } afu;
                afu.u[0] = x0; afu.u[1] = x1; afu.u[2] = y0; afu.u[3] = y1;
                af[mb] = afu.v;   // P[q=ln][keys 8*quad .. 8*quad+7]
            }

            // O += P V; vf shared by both q-tiles
            #pragma unroll
            for (int db = 0; db < 8; ++db) {
                bf16x8 vf = *(const bf16x8*)(vsb + (size_t)(db * 16 + ln) * VS_LDW + quad * 8);
                #pragma unroll
                for (int mb = 0; mb < 2; ++mb)
                    Oa[mb][db] = __builtin_amdgcn_mfma_f32_16x16x32_bf16(
                        af[mb], vf, Oa[mb][db], 0, 0, 0);
            }
        }
    }

    // ---- l reduce across quads + epilogue, per q-tile ----
    const int b = bh >> 3, h = bh & 7;
    #pragma unroll
    for (int mb = 0; mb < 2; ++mb) {
        float ltot = l_loc[mb];
        ltot += __shfl_xor(ltot, 16);
        ltot += __shfl_xor(ltot, 32);
        #pragma unroll
        for (int r = 0; r < 4; ++r) {
            const float inv = 1.0f / __shfl(ltot, quad * 4 + r);
            const int tok = q0 + mb * 16 + quad * 4 + r;
            u16* op = aout + ((size_t)(b * SEQ + tok)) * CC + h * HD + ln;
            #pragma unroll
            for (int db = 0; db < 8; ++db) op[db * 16] = f2bf(Oa[mb][db][r] * inv);
        }
    }
}

// ---------------------------------------------------------------------------
// K3: output projection, 4-way K-split, coalesced A via LDS staging (R24,
// kept). M=8192, N=128, K=1024. grid 512, block 256 (4 waves); wave kh owns
// the K-quarter of the SAME 16 rows; waves 1-3 write fp32 partials to LDS,
// wave 0 sums + bias. A[16][1024] staged coalesced (8 passes x 256 thr x
// 16B) into As16 stride 1032; pT reads stay global (L2-resident).
// ---------------------------------------------------------------------------
#define PJ_LDW 1032
__global__ __launch_bounds__(256) void proj_kernel(
    const u16* __restrict__ A, const u16* __restrict__ pT,
    const float* __restrict__ pb, float* __restrict__ out)
{
    __shared__ __align__(16) u16 As16[16 * PJ_LDW];   // 33024 B
    __shared__ float Rs[3][16 * 132];                 // 25344 B
    const int tid = threadIdx.x;
    const int lane = tid & 63, kh = tid >> 6;
    const int ln = lane & 15, quad = lane >> 4;
    const int m0 = blockIdx.x * 16;

    // ---- stage A[16][1024] coalesced: pass p loads rows 2p..2p+1 ----
    {
        const int row = tid >> 7;            // 0..1
        const int col = (tid & 127) * 8;     // 0..1016
        #pragma unroll
        for (int p = 0; p < 8; ++p) {
            const int r = p * 2 + row;
            *(bf16x8*)&As16[(size_t)r * PJ_LDW + col] =
                *(const bf16x8*)&A[(size_t)(m0 + r) * CC + col];
        }
    }
    __syncthreads();

    f32x4 acc[8];
    #pragma unroll
    for (int nb = 0; nb < 8; ++nb)
        #pragma unroll
        for (int r = 0; r < 4; ++r) acc[nb][r] = 0.0f;

    const u16* ap = As16 + (size_t)ln * PJ_LDW + kh * 256 + quad * 8;
    const u16* bp = pT + (size_t)ln * CC + kh * 256 + quad * 8;

    #pragma unroll
    for (int kt = 0; kt < 8; ++kt) {
        bf16x8 af = *(const bf16x8*)(ap + kt * 32);
        #pragma unroll
        for (int nb = 0; nb < 8; ++nb) {
            bf16x8 bf = *(const bf16x8*)(bp + (size_t)nb * 16 * CC + kt * 32);
            acc[nb] = __builtin_amdgcn_mfma_f32_16x16x32_bf16(af, bf, acc[nb], 0, 0, 0);
        }
    }

    if (kh > 0) {
        #pragma unroll
        for (int nb = 0; nb < 8; ++nb)
            #pragma unroll
            for (int r = 0; r < 4; ++r)
                Rs[kh - 1][(quad * 4 + r) * 132 + nb * 16 + ln] = acc[nb][r];
    }
    __syncthreads();
    if (kh == 0) {
        #pragma unroll
        for (int nb = 0; nb < 8; ++nb) {
            const int c = nb * 16 + ln;
            const float bv = pb[c];
            #pragma unroll
            for (int r = 0; r < 4; ++r) {
                const int ri = (quad * 4 + r) * 132 + c;
                out[(size_t)(m0 + quad * 4 + r) * HD + c] =
                    acc[nb][r] + Rs[0][ri] + Rs[1][ri] + Rs[2][ri] + bv;
            }
        }
    }
}

// ---------------------------------------------------------------------------
extern "C" void kernel_launch(void* const* d_in, const int* in_sizes, int n_in,
                              void* d_out, int out_size, void* d_ws, size_t ws_size,
                              hipStream_t stream)
{
    const float* x    = (const float*)d_in[0];
    const float* bias = (const float*)d_in[1];
    const float* wq   = (const float*)d_in[2];
    const float* wqb  = (const float*)d_in[3];
    const float* wk   = (const float*)d_in[4];
    const float* wkb  = (const float*)d_in[5];
    const float* wv   = (const float*)d_in[6];
    const float* wvb  = (const float*)d_in[7];
    const float* pw   = (const float*)d_in[8];
    const float* pb   = (const float*)d_in[9];
    float* out = (float*)d_out;

    u16* ws = (u16*)d_ws;
    size_t off = 0;
    u16* xb  = ws + off; off += (size_t)8192 * IND;     // 4 MB
    u16* wqT = ws + off; off += (size_t)CC * IND;       // 512 KB
    u16* wkT = ws + off; off += (size_t)CC * IND;
    u16* wvT = ws + off; off += (size_t)CC * IND;
    u16* pT  = ws + off; off += (size_t)HD * CC;        // 256 KB
    u16* Qw  = ws + off; off += (size_t)BH * SEQ * HD;  // 16 MB
    u16* Kw  = ws + off; off += (size_t)BH * SEQ * HD;
    u16* Vtw = ws + off; off += (size_t)BH * HD * SEQ;
    u16* Aw  = ws + off; off += (size_t)8192 * CC;      // 16 MB

    prep_kernel<<<2944, 256, 0, stream>>>(x, xb, wq, wk, wv, wqT, wkT, wvT, pw, pT);
    qkv_kernel<<<dim3(64, 8, 3), 256, 0, stream>>>(
        xb, wqT, wkT, wvT, wqb, wkb, wvb, Qw, Kw, Vtw);
    attn_kernel<<<dim3(64, 8), 256, 0, stream>>>(Qw, Kw, Vtw, bias, Aw);
    proj_kernel<<<512, 256, 0, stream>>>(Aw, pT, pb, out);
}

// Round 12
// 177.750 us; speedup vs baseline: 1.0139x; 1.0139x over previous
//
#include <hip/hip_runtime.h>
#include <math.h>

#define SEQ  1024
#define IND  256
#define CC   1024
#define NH   8
#define HD   128
#define BH   64      // BATCH*NH

typedef __bf16 bf16x8 __attribute__((ext_vector_type(8)));
typedef __bf16 bf16x4 __attribute__((ext_vector_type(4)));
typedef float  f32x4  __attribute__((ext_vector_type(4)));
typedef unsigned short u16;

static constexpr float RSDK = 0.08838834764831845f;  // 1/sqrt(128)

__device__ __forceinline__ u16 f2bf(float f) {
    unsigned int u = __float_as_uint(f);
    u += 0x7fffu + ((u >> 16) & 1u);   // round-to-nearest-even
    return (u16)(u >> 16);
}

__device__ __forceinline__ unsigned cvt_pk_bf16(float lo, float hi) {
    unsigned r;
    asm("v_cvt_pk_bf16_f32 %0, %1, %2" : "=v"(r) : "v"(lo), "v"(hi));
    return r;
}

// ---------------------------------------------------------------------------
// P0: fused prep. 1D grid 2944, block 256.
//   id <  2048          : x fp32 -> bf16 (4 elems/thread)
//   2048 <= id < 2816   : wq/wk/wv [256][1024] -> bf16 [1024][256] transpose
//   2816 <= id < 2944   : proj_w [1024][128]  -> bf16 [128][1024] transpose
// ---------------------------------------------------------------------------
__global__ __launch_bounds__(256) void prep_kernel(
    const float* __restrict__ x, u16* __restrict__ xb,
    const float* __restrict__ w0, const float* __restrict__ w1, const float* __restrict__ w2,
    u16* __restrict__ o0, u16* __restrict__ o1, u16* __restrict__ o2,
    const float* __restrict__ pw, u16* __restrict__ pT)
{
    __shared__ float tile[32][33];
    const int id = blockIdx.x;

    if (id < 2048) {
        const int i = id * 256 + threadIdx.x;
        float4 v = ((const float4*)x)[i];
        ushort4 o;
        o.x = f2bf(v.x); o.y = f2bf(v.y); o.z = f2bf(v.z); o.w = f2bf(v.w);
        ((ushort4*)xb)[i] = o;
        return;
    }

    const float* in; u16* out; int R, C, c0, r0;
    if (id < 2816) {
        const int rem = id - 2048;
        const int z = rem >> 8;              // 0..2
        const int rem2 = rem & 255;
        in  = (z == 0) ? w0 : (z == 1) ? w1 : w2;
        out = (z == 0) ? o0 : (z == 1) ? o1 : o2;
        R = IND; C = CC;
        c0 = (rem2 & 31) * 32;               // 0..992
        r0 = (rem2 >> 5) * 32;               // 0..224
    } else {
        const int rem = id - 2816;
        in = pw; out = pT;
        R = CC; C = HD;
        c0 = (rem & 3) * 32;                 // 0..96
        r0 = (rem >> 2) * 32;                // 0..992
    }

    const int row = threadIdx.x >> 3, col4 = (threadIdx.x & 7) * 4;
    float4 v = *(const float4*)&in[(size_t)(r0 + row) * C + c0 + col4];
    tile[row][col4 + 0] = v.x; tile[row][col4 + 1] = v.y;
    tile[row][col4 + 2] = v.z; tile[row][col4 + 3] = v.w;
    __syncthreads();
    ushort4 o;
    o.x = f2bf(tile[col4 + 0][row]);
    o.y = f2bf(tile[col4 + 1][row]);
    o.z = f2bf(tile[col4 + 2][row]);
    o.w = f2bf(tile[col4 + 3][row]);
    *(ushort4*)&out[(size_t)(c0 + row) * R + r0 + col4] = o;
}

// ---------------------------------------------------------------------------
// K1: QKV MFMA GEMM — R23 hybrid (kept). M=8192,N=1024,K=256. grid (64,8,3),
// block 256. 128x128 tile, BK=64, PADDED rows (stride 72 u16) reg-staged.
// Q/K use SWAPPED operands mfma(bf, af) -> lane holds 4 consecutive d ->
// epilogue is 16 ushort4 stores/lane. V unswapped + transposed ushort4 path.
// ---------------------------------------------------------------------------
#define QKV_LDW 72
__global__ __launch_bounds__(256) void qkv_kernel(
    const u16* __restrict__ xb,
    const u16* __restrict__ wT0, const u16* __restrict__ wT1, const u16* __restrict__ wT2,
    const float* __restrict__ b0, const float* __restrict__ b1, const float* __restrict__ b2,
    u16* __restrict__ q_out, u16* __restrict__ k_out, u16* __restrict__ vt_out)
{
    const int mat = blockIdx.z;
    const u16* wT  = (mat == 0) ? wT0 : (mat == 1) ? wT1 : wT2;
    const float* wb = (mat == 0) ? b0 : (mat == 1) ? b1 : b2;
    const float scale = (mat == 0) ? RSDK : 1.0f;

    __shared__ __align__(16) u16 As[128 * QKV_LDW];
    __shared__ __align__(16) u16 Bs[128 * QKV_LDW];

    const int tid = threadIdx.x;
    const int lane = tid & 63, wave = tid >> 6;
    const int ln = lane & 15, quad = lane >> 4;
    const int m0 = blockIdx.x * 128;
    const int n0 = blockIdx.y * 128;
    const int wm = (wave & 1) * 64;
    const int wn = (wave >> 1) * 64;

    f32x4 acc[4][4];
    #pragma unroll
    for (int mb = 0; mb < 4; ++mb)
        #pragma unroll
        for (int nb = 0; nb < 4; ++nb)
            #pragma unroll
            for (int r = 0; r < 4; ++r) acc[mb][nb][r] = 0.0f;

    const int r8 = tid >> 3, pb8 = tid & 7;   // row-within-32, 16B block

    const u16* ag = xb + (size_t)(m0 + r8) * IND + pb8 * 8;
    const u16* bg = wT + (size_t)(n0 + r8) * IND + pb8 * 8;

    bf16x8 pa[4], pbv[4];
    #pragma unroll
    for (int c = 0; c < 4; ++c) {
        pa[c]  = *(const bf16x8*)(ag + (size_t)c * 32 * IND);
        pbv[c] = *(const bf16x8*)(bg + (size_t)c * 32 * IND);
    }

    for (int kt = 0; kt < 4; ++kt) {
        __syncthreads();
        #pragma unroll
        for (int c = 0; c < 4; ++c) {
            *(bf16x8*)(As + (size_t)(c * 32 + r8) * QKV_LDW + pb8 * 8) = pa[c];
            *(bf16x8*)(Bs + (size_t)(c * 32 + r8) * QKV_LDW + pb8 * 8) = pbv[c];
        }
        __syncthreads();
        if (kt < 3) {
            #pragma unroll
            for (int c = 0; c < 4; ++c) {
                pa[c]  = *(const bf16x8*)(ag + (size_t)c * 32 * IND + (kt + 1) * 64);
                pbv[c] = *(const bf16x8*)(bg + (size_t)c * 32 * IND + (kt + 1) * 64);
            }
        }
        #pragma unroll
        for (int ks = 0; ks < 2; ++ks) {
            bf16x8 af[4], bf[4];
            #pragma unroll
            for (int mb = 0; mb < 4; ++mb)
                af[mb] = *(const bf16x8*)(As + (size_t)(wm + mb * 16 + ln) * QKV_LDW
                                             + (ks * 4 + quad) * 8);
            #pragma unroll
            for (int nb = 0; nb < 4; ++nb)
                bf[nb] = *(const bf16x8*)(Bs + (size_t)(wn + nb * 16 + ln) * QKV_LDW
                                             + (ks * 4 + quad) * 8);
            if (mat != 2) {
                // swapped: acc[mb][nb][r] = C[m=mb*16+ln][n=nb*16+quad*4+r]
                #pragma unroll
                for (int mb = 0; mb < 4; ++mb)
                    #pragma unroll
                    for (int nb = 0; nb < 4; ++nb)
                        acc[mb][nb] = __builtin_amdgcn_mfma_f32_16x16x32_bf16(
                            bf[nb], af[mb], acc[mb][nb], 0, 0, 0);
            } else {
                // unswapped: acc[mb][nb][r] = C[m=mb*16+quad*4+r][n=nb*16+ln]
                #pragma unroll
                for (int mb = 0; mb < 4; ++mb)
                    #pragma unroll
                    for (int nb = 0; nb < 4; ++nb)
                        acc[mb][nb] = __builtin_amdgcn_mfma_f32_16x16x32_bf16(
                            af[mb], bf[nb], acc[mb][nb], 0, 0, 0);
            }
        }
    }

    if (mat != 2) {
        u16* outp = (mat == 0) ? q_out : k_out;
        const int h = n0 >> 7;   // one head per n-tile
        float4 bv[4];
        #pragma unroll
        for (int nb = 0; nb < 4; ++nb)
            bv[nb] = *(const float4*)&wb[n0 + wn + nb * 16 + quad * 4];
        #pragma unroll
        for (int mb = 0; mb < 4; ++mb) {
            const int m = m0 + wm + mb * 16 + ln;
            const int b = m >> 10, tok = m & 1023;
            u16* orow = outp + ((size_t)(b * NH + h) * SEQ + tok) * HD;
            #pragma unroll
            for (int nb = 0; nb < 4; ++nb) {
                const int d0 = wn + nb * 16 + quad * 4;
                ushort4 o;
                o.x = f2bf((acc[mb][nb][0] + bv[nb].x) * scale);
                o.y = f2bf((acc[mb][nb][1] + bv[nb].y) * scale);
                o.z = f2bf((acc[mb][nb][2] + bv[nb].z) * scale);
                o.w = f2bf((acc[mb][nb][3] + bv[nb].w) * scale);
                *(ushort4*)&orow[d0] = o;
            }
        }
    } else {
        // V: fused transpose -> Vt [bh][d][n]; 4 consecutive tokens per store
        #pragma unroll
        for (int nb = 0; nb < 4; ++nb) {
            const int c = n0 + wn + nb * 16 + ln;
            const float bv = wb[c];
            const int h = c >> 7, d = c & 127;
            #pragma unroll
            for (int mb = 0; mb < 4; ++mb) {
                const int m = m0 + wm + mb * 16 + quad * 4;
                const int b = m >> 10, tok0 = m & 1023;
                ushort4 o;
                o.x = f2bf(acc[mb][nb][0] + bv);
                o.y = f2bf(acc[mb][nb][1] + bv);
                o.z = f2bf(acc[mb][nb][2] + bv);
                o.w = f2bf(acc[mb][nb][3] + bv);
                *(ushort4*)&vt_out[((size_t)(b * NH + h) * HD + d) * SEQ + tok0] = o;
            }
        }
    }
}

// ---------------------------------------------------------------------------
// K2: flash attention, MFMA. R26: R20-EXACT structure + s_setprio(1) around
// MFMA clusters (T5). Wave owns 32 q-rows (2 q-tiles) sharing one set of
// K/V fragment reads. grid (64 bh, 8 q-blocks), block 256,
// launch_bounds(256,2), KVB=32, 2 barriers/kt.
// R25 post-mortem closed the barrier-granule frontier BOTH ways: staging-
// granule x2 (R25, -3%) and compute-granule x2 (R23, -9%) both lose ->
// barriers are not the stall; intra-granule dependency latency is. The one
// cheap lever matching that diagnosis: setprio(1) on the MFMA clusters so
// the MFMA-entering wave preempts the other (independent, phase-diverse)
// block's wave on the same SIMD. Evidence: +4-7% attn (phase-diverse,
// m191-class — our 2 independent blocks/CU qualify), null only for
// barrier-lockstep waves. Zero arithmetic change -> bit-exact.
// Pre-commit: |delta| < 2us -> setprio closed AND attn declared at its
// structural floor for this session (remaining lever is an 8-phase counted-
// vmcnt rewrite — new sync template, needs race screening; R18 precedent).
// Closed frontiers: R18 single-barrier dbuf (RACE); R19 K-direct-global
// (2.4x); R21 key-split 512-thr (spill, 2.2x); R23 KVB=64 (+9%); R25
// double-staging (+3%). SQ_LDS_BANK_CONFLICT is structural 2-way
// accounting — not a lever. Other negatives: XOR swizzle (R3/4), P
// pair-pack LDS (R7), V-direct (R9), bias-as-C (R13), exp2 fold (R14).
// Unnormalized softmax (|s| <~ 10 << 88), p = exp(s), l in regs,
// in-register P via swapped QK^T + cvt_pk/permlane 4-quad transpose.
// Ks: [32 k][128 d] stride 136 u16; Vs: [128 d][32 k] stride 40 u16.
// ---------------------------------------------------------------------------
#define KVB    32
#define KS_LDW 136
#define VS_LDW 40
__global__ __launch_bounds__(256, 2) void attn_kernel(
    const u16* __restrict__ Q, const u16* __restrict__ K,
    const u16* __restrict__ Vt, const float* __restrict__ bias,
    u16* __restrict__ aout)
{
    __shared__ __align__(16) u16 Ks[KVB * KS_LDW];        // 8704 B
    __shared__ __align__(16) u16 Vs[128 * VS_LDW];        // 10240 B

    const int tid = threadIdx.x;
    const int lane = tid & 63, wave = tid >> 6;
    const int ln = lane & 15, quad = lane >> 4;
    const int bh = blockIdx.x;
    const int q0 = blockIdx.y * 128 + wave * 32;

    bf16x8 qf[2][4];
    #pragma unroll
    for (int mb = 0; mb < 2; ++mb) {
        const u16* qp = Q + ((size_t)bh * SEQ + q0 + mb * 16 + ln) * HD + quad * 8;
        #pragma unroll
        for (int ks = 0; ks < 4; ++ks) qf[mb][ks] = *(const bf16x8*)(qp + ks * 32);
    }

    f32x4 Oa[2][8];
    #pragma unroll
    for (int mb = 0; mb < 2; ++mb)
        #pragma unroll
        for (int db = 0; db < 8; ++db)
            #pragma unroll
            for (int r = 0; r < 4; ++r) Oa[mb][db][r] = 0.0f;
    float l_loc[2] = {0.0f, 0.0f};   // partial l for query ln, per q-tile

    const u16* Kg0 = K  + (size_t)bh * SEQ * HD;
    const u16* Vg0 = Vt + (size_t)bh * HD * SEQ;
    // bias rows for THIS lane's queries (ln per tile); float4 in key dim
    const float* brow0 = bias + (size_t)(q0 + ln) * SEQ + quad * 4;
    const float* brow1 = brow0 + (size_t)16 * SEQ;

    // staging indices (R17-exact)
    const int r16 = tid >> 4, pb16 = tid & 15;   // K: 16 rows/pass
    const int r4  = tid >> 2, pb4  = tid & 3;    // V: 64 rows/pass

    const u16* kg = Kg0 + (size_t)r16 * HD + pb16 * 8;   // + kt*KVB*HD + c*16*HD
    const u16* vg = Vg0 + (size_t)r4 * SEQ + pb4 * 8;    // + c*64*SEQ + kt*KVB

    bf16x8 kp[2], vp[2];
    #pragma unroll
    for (int c = 0; c < 2; ++c) {
        kp[c] = *(const bf16x8*)(kg + (size_t)c * 16 * HD);
        vp[c] = *(const bf16x8*)(vg + (size_t)c * 64 * SEQ);
    }

    // bias prefetch for kt=0: [mb][nb] = keys nb*16 + quad*4 + {0..3}
    float4 bpre[2][2];
    #pragma unroll
    for (int mb = 0; mb < 2; ++mb)
        #pragma unroll
        for (int nb = 0; nb < 2; ++nb)
            bpre[mb][nb] = *(const float4*)((mb ? brow1 : brow0) + nb * 16);

    for (int kt = 0; kt < 32; ++kt) {
        __syncthreads();
        #pragma unroll
        for (int c = 0; c < 2; ++c) {
            *(bf16x8*)(Ks + (size_t)(c * 16 + r16) * KS_LDW + pb16 * 8) = kp[c];
            *(bf16x8*)(Vs + (size_t)(c * 64 + r4) * VS_LDW + pb4 * 8)   = vp[c];
        }
        __syncthreads();

        // prefetch next K/V tile (off critical path)
        if (kt < 31) {
            #pragma unroll
            for (int c = 0; c < 2; ++c) {
                kp[c] = *(const bf16x8*)(kg + (size_t)(kt + 1) * KVB * HD + (size_t)c * 16 * HD);
                vp[c] = *(const bf16x8*)(vg + (size_t)c * 64 * SEQ + (kt + 1) * KVB);
            }
        }

        // ---- S^T = K Q^T (swapped); kf shared by both q-tiles ----
        float p8[2][2][4];
        #pragma unroll
        for (int nb = 0; nb < 2; ++nb) {
            const u16* kr = Ks + (size_t)(nb * 16 + ln) * KS_LDW;
            bf16x8 kf[4];
            #pragma unroll
            for (int ks = 0; ks < 4; ++ks)
                kf[ks] = *(const bf16x8*)(kr + (ks * 4 + quad) * 8);
            #pragma unroll
            for (int mb = 0; mb < 2; ++mb) {
                f32x4 s;
                #pragma unroll
                for (int r = 0; r < 4; ++r) s[r] = 0.0f;
                __builtin_amdgcn_s_setprio(1);
                #pragma unroll
                for (int ks = 0; ks < 4; ++ks)
                    s = __builtin_amdgcn_mfma_f32_16x16x32_bf16(kf[ks], qf[mb][ks], s, 0, 0, 0);
                __builtin_amdgcn_s_setprio(0);
                #pragma unroll
                for (int r = 0; r < 4; ++r) {
                    const float p = __expf(s[r] + bpre[mb][nb][r]);
                    l_loc[mb] += p;
                    p8[mb][nb][r] = p;
                }
            }
        }

        // bias for kt+1 (after last use of bpre; hidden under PV)
        if (kt < 31) {
            #pragma unroll
            for (int mb = 0; mb < 2; ++mb)
                #pragma unroll
                for (int nb = 0; nb < 2; ++nb)
                    bpre[mb][nb] = *(const float4*)((mb ? brow1 : brow0)
                                                    + (kt + 1) * KVB + nb * 16);
        }

        // ---- P -> A fragments: pure-register 4-quad transpose, per tile ----
        bf16x8 af[2];
        #pragma unroll
        for (int mb = 0; mb < 2; ++mb) {
            unsigned x0 = cvt_pk_bf16(p8[mb][0][0], p8[mb][0][1]);
            unsigned x1 = cvt_pk_bf16(p8[mb][0][2], p8[mb][0][3]);
            unsigned y0 = cvt_pk_bf16(p8[mb][1][0], p8[mb][1][1]);
            unsigned y1 = cvt_pk_bf16(p8[mb][1][2], p8[mb][1][3]);
            asm("v_permlane32_swap_b32 %0, %1" : "+v"(x0), "+v"(y0));
            asm("v_permlane32_swap_b32 %0, %1" : "+v"(x1), "+v"(y1));
            asm("v_permlane16_swap_b32 %0, %1" : "+v"(x0), "+v"(y0));
            asm("v_permlane16_swap_b32 %0, %1" : "+v"(x1), "+v"(y1));
            union { unsigned u[4]; bf16x8 v; } afu;
            afu.u[0] = x0; afu.u[1] = x1; afu.u[2] = y0; afu.u[3] = y1;
            af[mb] = afu.v;   // P[q=ln][keys 8*quad .. 8*quad+7]
        }

        // ---- O += P V; vf shared by both q-tiles ----
        __builtin_amdgcn_s_setprio(1);
        #pragma unroll
        for (int db = 0; db < 8; ++db) {
            bf16x8 vf = *(const bf16x8*)(Vs + (size_t)(db * 16 + ln) * VS_LDW + quad * 8);
            #pragma unroll
            for (int mb = 0; mb < 2; ++mb)
                Oa[mb][db] = __builtin_amdgcn_mfma_f32_16x16x32_bf16(
                    af[mb], vf, Oa[mb][db], 0, 0, 0);
        }
        __builtin_amdgcn_s_setprio(0);
    }

    // ---- l reduce across quads + epilogue, per q-tile ----
    const int b = bh >> 3, h = bh & 7;
    #pragma unroll
    for (int mb = 0; mb < 2; ++mb) {
        float ltot = l_loc[mb];
        ltot += __shfl_xor(ltot, 16);
        ltot += __shfl_xor(ltot, 32);
        #pragma unroll
        for (int r = 0; r < 4; ++r) {
            const float inv = 1.0f / __shfl(ltot, quad * 4 + r);
            const int tok = q0 + mb * 16 + quad * 4 + r;
            u16* op = aout + ((size_t)(b * SEQ + tok)) * CC + h * HD + ln;
            #pragma unroll
            for (int db = 0; db < 8; ++db) op[db * 16] = f2bf(Oa[mb][db][r] * inv);
        }
    }
}

// ---------------------------------------------------------------------------
// K3: output projection, 4-way K-split, coalesced A via LDS staging (R24,
// kept). M=8192, N=128, K=1024. grid 512, block 256 (4 waves); wave kh owns
// the K-quarter of the SAME 16 rows; waves 1-3 write fp32 partials to LDS,
// wave 0 sums + bias. A[16][1024] staged coalesced (8 passes x 256 thr x
// 16B) into As16 stride 1032; pT reads stay global (L2-resident).
// ---------------------------------------------------------------------------
#define PJ_LDW 1032
__global__ __launch_bounds__(256) void proj_kernel(
    const u16* __restrict__ A, const u16* __restrict__ pT,
    const float* __restrict__ pb, float* __restrict__ out)
{
    __shared__ __align__(16) u16 As16[16 * PJ_LDW];   // 33024 B
    __shared__ float Rs[3][16 * 132];                 // 25344 B
    const int tid = threadIdx.x;
    const int lane = tid & 63, kh = tid >> 6;
    const int ln = lane & 15, quad = lane >> 4;
    const int m0 = blockIdx.x * 16;

    // ---- stage A[16][1024] coalesced: pass p loads rows 2p..2p+1 ----
    {
        const int row = tid >> 7;            // 0..1
        const int col = (tid & 127) * 8;     // 0..1016
        #pragma unroll
        for (int p = 0; p < 8; ++p) {
            const int r = p * 2 + row;
            *(bf16x8*)&As16[(size_t)r * PJ_LDW + col] =
                *(const bf16x8*)&A[(size_t)(m0 + r) * CC + col];
        }
    }
    __syncthreads();

    f32x4 acc[8];
    #pragma unroll
    for (int nb = 0; nb < 8; ++nb)
        #pragma unroll
        for (int r = 0; r < 4; ++r) acc[nb][r] = 0.0f;

    const u16* ap = As16 + (size_t)ln * PJ_LDW + kh * 256 + quad * 8;
    const u16* bp = pT + (size_t)ln * CC + kh * 256 + quad * 8;

    #pragma unroll
    for (int kt = 0; kt < 8; ++kt) {
        bf16x8 af = *(const bf16x8*)(ap + kt * 32);
        #pragma unroll
        for (int nb = 0; nb < 8; ++nb) {
            bf16x8 bf = *(const bf16x8*)(bp + (size_t)nb * 16 * CC + kt * 32);
            acc[nb] = __builtin_amdgcn_mfma_f32_16x16x32_bf16(af, bf, acc[nb], 0, 0, 0);
        }
    }

    if (kh > 0) {
        #pragma unroll
        for (int nb = 0; nb < 8; ++nb)
            #pragma unroll
            for (int r = 0; r < 4; ++r)
                Rs[kh - 1][(quad * 4 + r) * 132 + nb * 16 + ln] = acc[nb][r];
    }
    __syncthreads();
    if (kh == 0) {
        #pragma unroll
        for (int nb = 0; nb < 8; ++nb) {
            const int c = nb * 16 + ln;
            const float bv = pb[c];
            #pragma unroll
            for (int r = 0; r < 4; ++r) {
                const int ri = (quad * 4 + r) * 132 + c;
                out[(size_t)(m0 + quad * 4 + r) * HD + c] =
                    acc[nb][r] + Rs[0][ri] + Rs[1][ri] + Rs[2][ri] + bv;
            }
        }
    }
}

// ---------------------------------------------------------------------------
extern "C" void kernel_launch(void* const* d_in, const int* in_sizes, int n_in,
                              void* d_out, int out_size, void* d_ws, size_t ws_size,
                              hipStream_t stream)
{
    const float* x    = (const float*)d_in[0];
    const float* bias = (const float*)d_in[1];
    const float* wq   = (const float*)d_in[2];
    const float* wqb  = (const float*)d_in[3];
    const float* wk   = (const float*)d_in[4];
    const float* wkb  = (const float*)d_in[5];
    const float* wv   = (const float*)d_in[6];
    const float* wvb  = (const float*)d_in[7];
    const float* pw   = (const float*)d_in[8];
    const float* pb   = (const float*)d_in[9];
    float* out = (float*)d_out;

    u16* ws = (u16*)d_ws;
    size_t off = 0;
    u16* xb  = ws + off; off += (size_t)8192 * IND;     // 4 MB
    u16* wqT = ws + off; off += (size_t)CC * IND;       // 512 KB
    u16* wkT = ws + off; off += (size_t)CC * IND;
    u16* wvT = ws + off; off += (size_t)CC * IND;
    u16* pT  = ws + off; off += (size_t)HD * CC;        // 256 KB
    u16* Qw  = ws + off; off += (size_t)BH * SEQ * HD;  // 16 MB
    u16* Kw  = ws + off; off += (size_t)BH * SEQ * HD;
    u16* Vtw = ws + off; off += (size_t)BH * HD * SEQ;
    u16* Aw  = ws + off; off += (size_t)8192 * CC;      // 16 MB

    prep_kernel<<<2944, 256, 0, stream>>>(x, xb, wq, wk, wv, wqT, wkT, wvT, pw, pT);
    qkv_kernel<<<dim3(64, 8, 3), 256, 0, stream>>>(
        xb, wqT, wkT, wvT, wqb, wkb, wvb, Qw, Kw, Vtw);
    attn_kernel<<<dim3(64, 8), 256, 0, stream>>>(Qw, Kw, Vtw, bias, Aw);
    proj_kernel<<<512, 256, 0, stream>>>(Aw, pT, pb, out);
}

// Round 13
// 177.739 us; speedup vs baseline: 1.0140x; 1.0001x over previous
//
#include <hip/hip_runtime.h>
#include <math.h>

#define SEQ  1024
#define IND  256
#define CC   1024
#define NH   8
#define HD   128
#define BH   64      // BATCH*NH

typedef __bf16 bf16x8 __attribute__((ext_vector_type(8)));
typedef __bf16 bf16x4 __attribute__((ext_vector_type(4)));
typedef float  f32x4  __attribute__((ext_vector_type(4)));
typedef unsigned short u16;

static constexpr float RSDK = 0.08838834764831845f;  // 1/sqrt(128)

__device__ __forceinline__ u16 f2bf(float f) {
    unsigned int u = __float_as_uint(f);
    u += 0x7fffu + ((u >> 16) & 1u);   // round-to-nearest-even
    return (u16)(u >> 16);
}

__device__ __forceinline__ unsigned cvt_pk_bf16(float lo, float hi) {
    unsigned r;
    asm("v_cvt_pk_bf16_f32 %0, %1, %2" : "=v"(r) : "v"(lo), "v"(hi));
    return r;
}

// load 8 fp32 and convert to bf16x8 in-register (RNE == f2bf bit-exact)
__device__ __forceinline__ bf16x8 ld8_cvt(const float* p) {
    float4 lo = *(const float4*)p;
    float4 hi = *(const float4*)(p + 4);
    union { unsigned u[4]; bf16x8 v; } c8;
    c8.u[0] = cvt_pk_bf16(lo.x, lo.y);
    c8.u[1] = cvt_pk_bf16(lo.z, lo.w);
    c8.u[2] = cvt_pk_bf16(hi.x, hi.y);
    c8.u[3] = cvt_pk_bf16(hi.z, hi.w);
    return c8.v;
}

// ---------------------------------------------------------------------------
// P0: prep — transposes ONLY (R27: x->bf16 cast fused into qkv staging;
// xb buffer and the 2048 conversion blocks deleted). 1D grid 896, block 256.
//   id <  768          : wq/wk/wv [256][1024] -> bf16 [1024][256] transpose
//   768 <= id < 896    : proj_w [1024][128]  -> bf16 [128][1024] transpose
// ---------------------------------------------------------------------------
__global__ __launch_bounds__(256) void prep_kernel(
    const float* __restrict__ w0, const float* __restrict__ w1, const float* __restrict__ w2,
    u16* __restrict__ o0, u16* __restrict__ o1, u16* __restrict__ o2,
    const float* __restrict__ pw, u16* __restrict__ pT)
{
    __shared__ float tile[32][33];
    const int id = blockIdx.x;

    const float* in; u16* out; int R, C, c0, r0;
    if (id < 768) {
        const int z = id >> 8;               // 0..2
        const int rem2 = id & 255;
        in  = (z == 0) ? w0 : (z == 1) ? w1 : w2;
        out = (z == 0) ? o0 : (z == 1) ? o1 : o2;
        R = IND; C = CC;
        c0 = (rem2 & 31) * 32;               // 0..992
        r0 = (rem2 >> 5) * 32;               // 0..224
    } else {
        const int rem = id - 768;
        in = pw; out = pT;
        R = CC; C = HD;
        c0 = (rem & 3) * 32;                 // 0..96
        r0 = (rem >> 2) * 32;                // 0..992
    }

    const int row = threadIdx.x >> 3, col4 = (threadIdx.x & 7) * 4;
    float4 v = *(const float4*)&in[(size_t)(r0 + row) * C + c0 + col4];
    tile[row][col4 + 0] = v.x; tile[row][col4 + 1] = v.y;
    tile[row][col4 + 2] = v.z; tile[row][col4 + 3] = v.w;
    __syncthreads();
    ushort4 o;
    o.x = f2bf(tile[col4 + 0][row]);
    o.y = f2bf(tile[col4 + 1][row]);
    o.z = f2bf(tile[col4 + 2][row]);
    o.w = f2bf(tile[col4 + 3][row]);
    *(ushort4*)&out[(size_t)(c0 + row) * R + r0 + col4] = o;
}

// ---------------------------------------------------------------------------
// K1: QKV MFMA GEMM — R27: A-operand read DIRECTLY from fp32 x with
// in-register cvt_pk_bf16 (RNE == prep's f2bf -> bf16 inputs bit-identical;
// xb round-trip eliminated). Per-lane staging load is 2x float4 = 32B,
// 256B-contiguous per 8-lane group (coalescing preserved). Otherwise
// R23-hybrid: M=8192,N=1024,K=256, grid (64,8,3), block 256, 128x128 tile,
// BK=64, PADDED LDS rows (stride 72 u16) reg-staged. Q/K use SWAPPED
// operands mfma(bf, af) -> 16 ushort4 stores/lane epilogue. V unswapped +
// transposed ushort4 path. h = blockIdx.y.
// ---------------------------------------------------------------------------
#define QKV_LDW 72
__global__ __launch_bounds__(256) void qkv_kernel(
    const float* __restrict__ x,
    const u16* __restrict__ wT0, const u16* __restrict__ wT1, const u16* __restrict__ wT2,
    const float* __restrict__ b0, const float* __restrict__ b1, const float* __restrict__ b2,
    u16* __restrict__ q_out, u16* __restrict__ k_out, u16* __restrict__ vt_out)
{
    const int mat = blockIdx.z;
    const u16* wT  = (mat == 0) ? wT0 : (mat == 1) ? wT1 : wT2;
    const float* wb = (mat == 0) ? b0 : (mat == 1) ? b1 : b2;
    const float scale = (mat == 0) ? RSDK : 1.0f;

    __shared__ __align__(16) u16 As[128 * QKV_LDW];
    __shared__ __align__(16) u16 Bs[128 * QKV_LDW];

    const int tid = threadIdx.x;
    const int lane = tid & 63, wave = tid >> 6;
    const int ln = lane & 15, quad = lane >> 4;
    const int m0 = blockIdx.x * 128;
    const int n0 = blockIdx.y * 128;
    const int wm = (wave & 1) * 64;
    const int wn = (wave >> 1) * 64;

    f32x4 acc[4][4];
    #pragma unroll
    for (int mb = 0; mb < 4; ++mb)
        #pragma unroll
        for (int nb = 0; nb < 4; ++nb)
            #pragma unroll
            for (int r = 0; r < 4; ++r) acc[mb][nb][r] = 0.0f;

    const int r8 = tid >> 3, pb8 = tid & 7;   // row-within-32, 16B block

    const float* ag = x + (size_t)(m0 + r8) * IND + pb8 * 8;
    const u16*   bg = wT + (size_t)(n0 + r8) * IND + pb8 * 8;

    bf16x8 pa[4], pbv[4];
    #pragma unroll
    for (int c = 0; c < 4; ++c) {
        pa[c]  = ld8_cvt(ag + (size_t)c * 32 * IND);
        pbv[c] = *(const bf16x8*)(bg + (size_t)c * 32 * IND);
    }

    for (int kt = 0; kt < 4; ++kt) {
        __syncthreads();
        #pragma unroll
        for (int c = 0; c < 4; ++c) {
            *(bf16x8*)(As + (size_t)(c * 32 + r8) * QKV_LDW + pb8 * 8) = pa[c];
            *(bf16x8*)(Bs + (size_t)(c * 32 + r8) * QKV_LDW + pb8 * 8) = pbv[c];
        }
        __syncthreads();
        if (kt < 3) {
            #pragma unroll
            for (int c = 0; c < 4; ++c) {
                pa[c]  = ld8_cvt(ag + (size_t)c * 32 * IND + (kt + 1) * 64);
                pbv[c] = *(const bf16x8*)(bg + (size_t)c * 32 * IND + (kt + 1) * 64);
            }
        }
        #pragma unroll
        for (int ks = 0; ks < 2; ++ks) {
            bf16x8 af[4], bf[4];
            #pragma unroll
            for (int mb = 0; mb < 4; ++mb)
                af[mb] = *(const bf16x8*)(As + (size_t)(wm + mb * 16 + ln) * QKV_LDW
                                             + (ks * 4 + quad) * 8);
            #pragma unroll
            for (int nb = 0; nb < 4; ++nb)
                bf[nb] = *(const bf16x8*)(Bs + (size_t)(wn + nb * 16 + ln) * QKV_LDW
                                             + (ks * 4 + quad) * 8);
            if (mat != 2) {
                // swapped: acc[mb][nb][r] = C[m=mb*16+ln][n=nb*16+quad*4+r]
                #pragma unroll
                for (int mb = 0; mb < 4; ++mb)
                    #pragma unroll
                    for (int nb = 0; nb < 4; ++nb)
                        acc[mb][nb] = __builtin_amdgcn_mfma_f32_16x16x32_bf16(
                            bf[nb], af[mb], acc[mb][nb], 0, 0, 0);
            } else {
                // unswapped: acc[mb][nb][r] = C[m=mb*16+quad*4+r][n=nb*16+ln]
                #pragma unroll
                for (int mb = 0; mb < 4; ++mb)
                    #pragma unroll
                    for (int nb = 0; nb < 4; ++nb)
                        acc[mb][nb] = __builtin_amdgcn_mfma_f32_16x16x32_bf16(
                            af[mb], bf[nb], acc[mb][nb], 0, 0, 0);
            }
        }
    }

    if (mat != 2) {
        u16* outp = (mat == 0) ? q_out : k_out;
        const int h = n0 >> 7;   // one head per n-tile
        float4 bv[4];
        #pragma unroll
        for (int nb = 0; nb < 4; ++nb)
            bv[nb] = *(const float4*)&wb[n0 + wn + nb * 16 + quad * 4];
        #pragma unroll
        for (int mb = 0; mb < 4; ++mb) {
            const int m = m0 + wm + mb * 16 + ln;
            const int b = m >> 10, tok = m & 1023;
            u16* orow = outp + ((size_t)(b * NH + h) * SEQ + tok) * HD;
            #pragma unroll
            for (int nb = 0; nb < 4; ++nb) {
                const int d0 = wn + nb * 16 + quad * 4;
                ushort4 o;
                o.x = f2bf((acc[mb][nb][0] + bv[nb].x) * scale);
                o.y = f2bf((acc[mb][nb][1] + bv[nb].y) * scale);
                o.z = f2bf((acc[mb][nb][2] + bv[nb].z) * scale);
                o.w = f2bf((acc[mb][nb][3] + bv[nb].w) * scale);
                *(ushort4*)&orow[d0] = o;
            }
        }
    } else {
        // V: fused transpose -> Vt [bh][d][n]; 4 consecutive tokens per store
        #pragma unroll
        for (int nb = 0; nb < 4; ++nb) {
            const int c = n0 + wn + nb * 16 + ln;
            const float bv = wb[c];
            const int h = c >> 7, d = c & 127;
            #pragma unroll
            for (int mb = 0; mb < 4; ++mb) {
                const int m = m0 + wm + mb * 16 + quad * 4;
                const int b = m >> 10, tok0 = m & 1023;
                ushort4 o;
                o.x = f2bf(acc[mb][nb][0] + bv);
                o.y = f2bf(acc[mb][nb][1] + bv);
                o.z = f2bf(acc[mb][nb][2] + bv);
                o.w = f2bf(acc[mb][nb][3] + bv);
                *(ushort4*)&vt_out[((size_t)(b * NH + h) * HD + d) * SEQ + tok0] = o;
            }
        }
    }
}

// ---------------------------------------------------------------------------
// K2: flash attention, MFMA. R26-EXACT (best measured: attn 55.4 us median).
// R20 structure + s_setprio(1) around MFMA clusters (T5, confirmed +2.5us
// within-probe R24->R26 with otherwise-identical counters). Wave owns 32
// q-rows (2 q-tiles) sharing one set of K/V fragment reads. grid (64 bh,
// 8 q-blocks), block 256, launch_bounds(256,2), KVB=32, 2 barriers/kt.
// Closed frontiers: R18 single-barrier dbuf (RACE); R19 K-direct-global
// (2.4x); R21 key-split 512-thr (spill, 2.2x); R23 KVB=64 (+9%); R25
// double-staging granule (+3%). Barrier overhead is NOT the stall (R25);
// intra-granule dependency latency is — setprio is the matching lever.
// SQ_LDS_BANK_CONFLICT is structural 2-way accounting — not a lever.
// Other negatives: XOR swizzle (R3/4), P pair-pack LDS (R7), V-direct (R9),
// bias-as-C (R13), exp2 fold (R14).
// Unnormalized softmax (|s| <~ 10 << 88), p = exp(s), l in regs,
// in-register P via swapped QK^T + cvt_pk/permlane 4-quad transpose.
// Ks: [32 k][128 d] stride 136 u16; Vs: [128 d][32 k] stride 40 u16.
// ---------------------------------------------------------------------------
#define KVB    32
#define KS_LDW 136
#define VS_LDW 40
__global__ __launch_bounds__(256, 2) void attn_kernel(
    const u16* __restrict__ Q, const u16* __restrict__ K,
    const u16* __restrict__ Vt, const float* __restrict__ bias,
    u16* __restrict__ aout)
{
    __shared__ __align__(16) u16 Ks[KVB * KS_LDW];        // 8704 B
    __shared__ __align__(16) u16 Vs[128 * VS_LDW];        // 10240 B

    const int tid = threadIdx.x;
    const int lane = tid & 63, wave = tid >> 6;
    const int ln = lane & 15, quad = lane >> 4;
    const int bh = blockIdx.x;
    const int q0 = blockIdx.y * 128 + wave * 32;

    bf16x8 qf[2][4];
    #pragma unroll
    for (int mb = 0; mb < 2; ++mb) {
        const u16* qp = Q + ((size_t)bh * SEQ + q0 + mb * 16 + ln) * HD + quad * 8;
        #pragma unroll
        for (int ks = 0; ks < 4; ++ks) qf[mb][ks] = *(const bf16x8*)(qp + ks * 32);
    }

    f32x4 Oa[2][8];
    #pragma unroll
    for (int mb = 0; mb < 2; ++mb)
        #pragma unroll
        for (int db = 0; db < 8; ++db)
            #pragma unroll
            for (int r = 0; r < 4; ++r) Oa[mb][db][r] = 0.0f;
    float l_loc[2] = {0.0f, 0.0f};   // partial l for query ln, per q-tile

    const u16* Kg0 = K  + (size_t)bh * SEQ * HD;
    const u16* Vg0 = Vt + (size_t)bh * HD * SEQ;
    // bias rows for THIS lane's queries (ln per tile); float4 in key dim
    const float* brow0 = bias + (size_t)(q0 + ln) * SEQ + quad * 4;
    const float* brow1 = brow0 + (size_t)16 * SEQ;

    // staging indices (R17-exact)
    const int r16 = tid >> 4, pb16 = tid & 15;   // K: 16 rows/pass
    const int r4  = tid >> 2, pb4  = tid & 3;    // V: 64 rows/pass

    const u16* kg = Kg0 + (size_t)r16 * HD + pb16 * 8;   // + kt*KVB*HD + c*16*HD
    const u16* vg = Vg0 + (size_t)r4 * SEQ + pb4 * 8;    // + c*64*SEQ + kt*KVB

    bf16x8 kp[2], vp[2];
    #pragma unroll
    for (int c = 0; c < 2; ++c) {
        kp[c] = *(const bf16x8*)(kg + (size_t)c * 16 * HD);
        vp[c] = *(const bf16x8*)(vg + (size_t)c * 64 * SEQ);
    }

    // bias prefetch for kt=0: [mb][nb] = keys nb*16 + quad*4 + {0..3}
    float4 bpre[2][2];
    #pragma unroll
    for (int mb = 0; mb < 2; ++mb)
        #pragma unroll
        for (int nb = 0; nb < 2; ++nb)
            bpre[mb][nb] = *(const float4*)((mb ? brow1 : brow0) + nb * 16);

    for (int kt = 0; kt < 32; ++kt) {
        __syncthreads();
        #pragma unroll
        for (int c = 0; c < 2; ++c) {
            *(bf16x8*)(Ks + (size_t)(c * 16 + r16) * KS_LDW + pb16 * 8) = kp[c];
            *(bf16x8*)(Vs + (size_t)(c * 64 + r4) * VS_LDW + pb4 * 8)   = vp[c];
        }
        __syncthreads();

        // prefetch next K/V tile (off critical path)
        if (kt < 31) {
            #pragma unroll
            for (int c = 0; c < 2; ++c) {
                kp[c] = *(const bf16x8*)(kg + (size_t)(kt + 1) * KVB * HD + (size_t)c * 16 * HD);
                vp[c] = *(const bf16x8*)(vg + (size_t)c * 64 * SEQ + (kt + 1) * KVB);
            }
        }

        // ---- S^T = K Q^T (swapped); kf shared by both q-tiles ----
        float p8[2][2][4];
        #pragma unroll
        for (int nb = 0; nb < 2; ++nb) {
            const u16* kr = Ks + (size_t)(nb * 16 + ln) * KS_LDW;
            bf16x8 kf[4];
            #pragma unroll
            for (int ks = 0; ks < 4; ++ks)
                kf[ks] = *(const bf16x8*)(kr + (ks * 4 + quad) * 8);
            #pragma unroll
            for (int mb = 0; mb < 2; ++mb) {
                f32x4 s;
                #pragma unroll
                for (int r = 0; r < 4; ++r) s[r] = 0.0f;
                __builtin_amdgcn_s_setprio(1);
                #pragma unroll
                for (int ks = 0; ks < 4; ++ks)
                    s = __builtin_amdgcn_mfma_f32_16x16x32_bf16(kf[ks], qf[mb][ks], s, 0, 0, 0);
                __builtin_amdgcn_s_setprio(0);
                #pragma unroll
                for (int r = 0; r < 4; ++r) {
                    const float p = __expf(s[r] + bpre[mb][nb][r]);
                    l_loc[mb] += p;
                    p8[mb][nb][r] = p;
                }
            }
        }

        // bias for kt+1 (after last use of bpre; hidden under PV)
        if (kt < 31) {
            #pragma unroll
            for (int mb = 0; mb < 2; ++mb)
                #pragma unroll
                for (int nb = 0; nb < 2; ++nb)
                    bpre[mb][nb] = *(const float4*)((mb ? brow1 : brow0)
                                                    + (kt + 1) * KVB + nb * 16);
        }

        // ---- P -> A fragments: pure-register 4-quad transpose, per tile ----
        bf16x8 af[2];
        #pragma unroll
        for (int mb = 0; mb < 2; ++mb) {
            unsigned x0 = cvt_pk_bf16(p8[mb][0][0], p8[mb][0][1]);
            unsigned x1 = cvt_pk_bf16(p8[mb][0][2], p8[mb][0][3]);
            unsigned y0 = cvt_pk_bf16(p8[mb][1][0], p8[mb][1][1]);
            unsigned y1 = cvt_pk_bf16(p8[mb][1][2], p8[mb][1][3]);
            asm("v_permlane32_swap_b32 %0, %1" : "+v"(x0), "+v"(y0));
            asm("v_permlane32_swap_b32 %0, %1" : "+v"(x1), "+v"(y1));
            asm("v_permlane16_swap_b32 %0, %1" : "+v"(x0), "+v"(y0));
            asm("v_permlane16_swap_b32 %0, %1" : "+v"(x1), "+v"(y1));
            union { unsigned u[4]; bf16x8 v; } afu;
            afu.u[0] = x0; afu.u[1] = x1; afu.u[2] = y0; afu.u[3] = y1;
            af[mb] = afu.v;   // P[q=ln][keys 8*quad .. 8*quad+7]
        }

        // ---- O += P V; vf shared by both q-tiles ----
        __builtin_amdgcn_s_setprio(1);
        #pragma unroll
        for (int db = 0; db < 8; ++db) {
            bf16x8 vf = *(const bf16x8*)(Vs + (size_t)(db * 16 + ln) * VS_LDW + quad * 8);
            #pragma unroll
            for (int mb = 0; mb < 2; ++mb)
                Oa[mb][db] = __builtin_amdgcn_mfma_f32_16x16x32_bf16(
                    af[mb], vf, Oa[mb][db], 0, 0, 0);
        }
        __builtin_amdgcn_s_setprio(0);
    }

    // ---- l reduce across quads + epilogue, per q-tile ----
    const int b = bh >> 3, h = bh & 7;
    #pragma unroll
    for (int mb = 0; mb < 2; ++mb) {
        float ltot = l_loc[mb];
        ltot += __shfl_xor(ltot, 16);
        ltot += __shfl_xor(ltot, 32);
        #pragma unroll
        for (int r = 0; r < 4; ++r) {
            const float inv = 1.0f / __shfl(ltot, quad * 4 + r);
            const int tok = q0 + mb * 16 + quad * 4 + r;
            u16* op = aout + ((size_t)(b * SEQ + tok)) * CC + h * HD + ln;
            #pragma unroll
            for (int db = 0; db < 8; ++db) op[db * 16] = f2bf(Oa[mb][db][r] * inv);
        }
    }
}

// ---------------------------------------------------------------------------
// K3: output projection, 4-way K-split, coalesced A via LDS staging (R24,
// kept). M=8192, N=128, K=1024. grid 512, block 256 (4 waves); wave kh owns
// the K-quarter of the SAME 16 rows; waves 1-3 write fp32 partials to LDS,
// wave 0 sums + bias. A[16][1024] staged coalesced (8 passes x 256 thr x
// 16B) into As16 stride 1032; pT reads stay global (L2-resident).
// ---------------------------------------------------------------------------
#define PJ_LDW 1032
__global__ __launch_bounds__(256) void proj_kernel(
    const u16* __restrict__ A, const u16* __restrict__ pT,
    const float* __restrict__ pb, float* __restrict__ out)
{
    __shared__ __align__(16) u16 As16[16 * PJ_LDW];   // 33024 B
    __shared__ float Rs[3][16 * 132];                 // 25344 B
    const int tid = threadIdx.x;
    const int lane = tid & 63, kh = tid >> 6;
    const int ln = lane & 15, quad = lane >> 4;
    const int m0 = blockIdx.x * 16;

    // ---- stage A[16][1024] coalesced: pass p loads rows 2p..2p+1 ----
    {
        const int row = tid >> 7;            // 0..1
        const int col = (tid & 127) * 8;     // 0..1016
        #pragma unroll
        for (int p = 0; p < 8; ++p) {
            const int r = p * 2 + row;
            *(bf16x8*)&As16[(size_t)r * PJ_LDW + col] =
                *(const bf16x8*)&A[(size_t)(m0 + r) * CC + col];
        }
    }
    __syncthreads();

    f32x4 acc[8];
    #pragma unroll
    for (int nb = 0; nb < 8; ++nb)
        #pragma unroll
        for (int r = 0; r < 4; ++r) acc[nb][r] = 0.0f;

    const u16* ap = As16 + (size_t)ln * PJ_LDW + kh * 256 + quad * 8;
    const u16* bp = pT + (size_t)ln * CC + kh * 256 + quad * 8;

    #pragma unroll
    for (int kt = 0; kt < 8; ++kt) {
        bf16x8 af = *(const bf16x8*)(ap + kt * 32);
        #pragma unroll
        for (int nb = 0; nb < 8; ++nb) {
            bf16x8 bf = *(const bf16x8*)(bp + (size_t)nb * 16 * CC + kt * 32);
            acc[nb] = __builtin_amdgcn_mfma_f32_16x16x32_bf16(af, bf, acc[nb], 0, 0, 0);
        }
    }

    if (kh > 0) {
        #pragma unroll
        for (int nb = 0; nb < 8; ++nb)
            #pragma unroll
            for (int r = 0; r < 4; ++r)
                Rs[kh - 1][(quad * 4 + r) * 132 + nb * 16 + ln] = acc[nb][r];
    }
    __syncthreads();
    if (kh == 0) {
        #pragma unroll
        for (int nb = 0; nb < 8; ++nb) {
            const int c = nb * 16 + ln;
            const float bv = pb[c];
            #pragma unroll
            for (int r = 0; r < 4; ++r) {
                const int ri = (quad * 4 + r) * 132 + c;
                out[(size_t)(m0 + quad * 4 + r) * HD + c] =
                    acc[nb][r] + Rs[0][ri] + Rs[1][ri] + Rs[2][ri] + bv;
            }
        }
    }
}

// ---------------------------------------------------------------------------
extern "C" void kernel_launch(void* const* d_in, const int* in_sizes, int n_in,
                              void* d_out, int out_size, void* d_ws, size_t ws_size,
                              hipStream_t stream)
{
    const float* x    = (const float*)d_in[0];
    const float* bias = (const float*)d_in[1];
    const float* wq   = (const float*)d_in[2];
    const float* wqb  = (const float*)d_in[3];
    const float* wk   = (const float*)d_in[4];
    const float* wkb  = (const float*)d_in[5];
    const float* wv   = (const float*)d_in[6];
    const float* wvb  = (const float*)d_in[7];
    const float* pw   = (const float*)d_in[8];
    const float* pb   = (const float*)d_in[9];
    float* out = (float*)d_out;

    u16* ws = (u16*)d_ws;
    size_t off = 0;
    u16* wqT = ws + off; off += (size_t)CC * IND;       // 512 KB
    u16* wkT = ws + off; off += (size_t)CC * IND;
    u16* wvT = ws + off; off += (size_t)CC * IND;
    u16* pT  = ws + off; off += (size_t)HD * CC;        // 256 KB
    u16* Qw  = ws + off; off += (size_t)BH * SEQ * HD;  // 16 MB
    u16* Kw  = ws + off; off += (size_t)BH * SEQ * HD;
    u16* Vtw = ws + off; off += (size_t)BH * HD * SEQ;
    u16* Aw  = ws + off; off += (size_t)8192 * CC;      // 16 MB

    prep_kernel<<<896, 256, 0, stream>>>(wq, wk, wv, wqT, wkT, wvT, pw, pT);
    qkv_kernel<<<dim3(64, 8, 3), 256, 0, stream>>>(
        x, wqT, wkT, wvT, wqb, wkb, wvb, Qw, Kw, Vtw);
    attn_kernel<<<dim3(64, 8), 256, 0, stream>>>(Qw, Kw, Vtw, bias, Aw);
    proj_kernel<<<512, 256, 0, stream>>>(Aw, pT, pb, out);
}